// Round 3
// baseline (189.940 us; speedup 1.0000x reference)
//
#include <hip/hip_runtime.h>
#include <hip/hip_bf16.h>
#include <hip/hip_cooperative_groups.h>
#include <math.h>

namespace cg = cooperative_groups;

// ---------------------------------------------------------------------------
// Rejection sampler (speculative decoding) for MI355X — single cooperative
// kernel. Phase 1: grid-stride segmented argmax over target_logits [T,V]
// (NS=16 segments/row; 576*16=9216 chunks over 1024 blocks = 9 each, perfectly
// balanced). 4 independent per-slot accumulators, strict '>' (monotone indices
// give first-occurrence tie-break for free). Phase 2 after grid.sync():
// block b finalizes batch row b from the NS partials per token.
// ---------------------------------------------------------------------------

typedef float f32x4 __attribute__((ext_vector_type(4)));

__device__ __forceinline__ void combine(float& bv, int& bi, float v, int i) {
    // prefer larger value; on tie prefer smaller index (jnp.argmax semantics)
    if (v > bv || (v == bv && i < bi)) { bv = v; bi = i; }
}

template <int BLOCK, int NS>
__global__ void __launch_bounds__(BLOCK)
fused_rejection_kernel(const float* __restrict__ logits, int vocab, int T,
                       const int* __restrict__ draft,
                       const int* __restrict__ cu,
                       const int* __restrict__ bonus,
                       float* __restrict__ ws_val, int* __restrict__ ws_idx,
                       int* __restrict__ out_tokens, int* __restrict__ out_bonus,
                       int B, int S) {
    const int tid = threadIdx.x;
    constexpr int NW = BLOCK / 64;
    __shared__ float sv[NW];
    __shared__ int   si[NW];
    __shared__ int   tok[32];                 // per-token argmax (S <= 31)

    const int seg_len = vocab / NS;           // 128000/16 = 8000 (4-aligned)
    const int nchunks = T * NS;

    // ---------------- Phase 1: per-(row,segment) argmax partials ----------
    for (int c = blockIdx.x; c < nchunks; c += gridDim.x) {
        const int row = c / NS;
        const int seg = c - row * NS;
        const int seg_beg = seg * seg_len;
        const int seg_end = (seg == NS - 1) ? vocab : seg_beg + seg_len;
        const float* rowp = logits + (size_t)row * (size_t)vocab;
        const f32x4* p4 = (const f32x4*)rowp;
        const int beg4 = seg_beg >> 2;
        const int end4 = seg_end >> 2;

        // 4 independent accumulators -> 4x shorter dep chains, no tie VALU
        float bv0 = -INFINITY, bv1 = -INFINITY, bv2 = -INFINITY, bv3 = -INFINITY;
        int   bj0 = 0, bj1 = 0, bj2 = 0, bj3 = 0;
        for (int j = beg4 + tid; j < end4; j += BLOCK) {
            f32x4 v = __builtin_nontemporal_load(&p4[j]);
            if (v.x > bv0) { bv0 = v.x; bj0 = j; }
            if (v.y > bv1) { bv1 = v.y; bj1 = j; }
            if (v.z > bv2) { bv2 = v.z; bj2 = j; }
            if (v.w > bv3) { bv3 = v.w; bj3 = j; }
        }
        float bv = bv0; int bi = (bj0 << 2);
        combine(bv, bi, bv1, (bj1 << 2) | 1);
        combine(bv, bi, bv2, (bj2 << 2) | 2);
        combine(bv, bi, bv3, (bj3 << 2) | 3);
        // scalar tail (vocab % 4 != 0 safety; empty for 128000)
        for (int j2 = (end4 << 2) + tid; j2 < seg_end; j2 += BLOCK)
            combine(bv, bi, rowp[j2], j2);

        #pragma unroll
        for (int off = 32; off >= 1; off >>= 1) {
            float ov = __shfl_down(bv, off, 64);
            int   oi = __shfl_down(bi, off, 64);
            combine(bv, bi, ov, oi);
        }
        if ((tid & 63) == 0) { sv[tid >> 6] = bv; si[tid >> 6] = bi; }
        __syncthreads();
        if (tid == 0) {
            #pragma unroll
            for (int w = 1; w < NW; ++w) combine(bv, bi, sv[w], si[w]);
            ws_val[c] = bv;
            ws_idx[c] = bi;
        }
        __syncthreads();                      // LDS reuse across chunks
    }

    cg::this_grid().sync();

    // ---------------- Phase 2: block b finalizes batch row b --------------
    for (int b = blockIdx.x; b < B; b += gridDim.x) {
        const int start = (b == 0) ? 0 : cu[b - 1];
        const int n = cu[b] - start;          // in [1, S]
        // NS lanes per token reduce the NS segment partials
        const int p = tid / NS;
        const int s = tid % NS;
        if (p < n && p < 32) {
            const int c = (start + p) * NS + s;
            float v = ws_val[c];
            int   i = ws_idx[c];
            #pragma unroll
            for (int off = NS / 2; off >= 1; off >>= 1) {
                float ov = __shfl_down(v, off, NS);
                int   oi = __shfl_down(i, off, NS);
                combine(v, i, ov, oi);
            }
            if (s == 0) tok[p] = i;
        }
        __syncthreads();
        if (tid == 0) {
            int* rowo = out_tokens + (size_t)b * (S + 1);
            bool rejected = false;
            int  processed = 0;
            for (int p2 = 0; p2 <= S; ++p2) {
                int val;
                if (p2 < n) {
                    if (!rejected) {
                        const int t = tok[p2];
                        val = t;
                        ++processed;
                        if (draft[start + p2] != t) rejected = true;
                    } else {
                        val = -1;
                    }
                } else if (p2 == n) {
                    val = rejected ? -1 : bonus[b];
                } else {
                    val = -1;
                }
                rowo[p2] = val;
            }
            out_bonus[b] = processed - 1 + (rejected ? 0 : 1);
        }
        __syncthreads();
    }
}

extern "C" void kernel_launch(void* const* d_in, const int* in_sizes, int n_in,
                              void* d_out, int out_size, void* d_ws, size_t ws_size,
                              hipStream_t stream) {
    // Inputs (setup_inputs order):
    //   0: draft_token_ids     int32 [T]
    //   1: num_spec_steps      int32 [1]   (derived host-side instead)
    //   2: cu_num_draft_tokens int32 [B]
    //   3: target_logits       float32 [T, V]
    //   4: bonus_token_ids     int32 [B]
    const int*   draft  = (const int*)d_in[0];
    const int*   cu     = (const int*)d_in[2];
    const float* logits = (const float*)d_in[3];
    const int*   bonus  = (const int*)d_in[4];

    int T     = in_sizes[0];
    int B     = in_sizes[2];
    int vocab = in_sizes[3] / T;
    int S     = out_size / B - 2;   // out = B*(S+1) + B

    constexpr int NS    = 16;       // segments per row
    constexpr int BLOCK = 256;      // 4 waves/block
    constexpr int GRID  = 1024;     // 4 blocks/CU -> all co-resident (coop)

    float* ws_val = (float*)d_ws;                 // T*NS floats
    int*   ws_idx = (int*)(ws_val + (size_t)T * NS);
    int* out_tokens = (int*)d_out;                // [B, S+1]
    int* out_bonus  = out_tokens + (size_t)B * (S + 1);

    void* args[] = {
        (void*)&logits, (void*)&vocab, (void*)&T,
        (void*)&draft, (void*)&cu, (void*)&bonus,
        (void*)&ws_val, (void*)&ws_idx,
        (void*)&out_tokens, (void*)&out_bonus,
        (void*)&B, (void*)&S,
    };
    hipLaunchCooperativeKernel((void*)fused_rejection_kernel<BLOCK, NS>,
                               dim3(GRID), dim3(BLOCK), args, 0, stream);
}

// Round 4
// 54.026 us; speedup vs baseline: 3.5157x; 3.5157x over previous
//
#include <hip/hip_runtime.h>
#include <hip/hip_bf16.h>
#include <math.h>

// ---------------------------------------------------------------------------
// Rejection sampler (speculative decoding) for MI355X — two kernels.
//
// Phase 1: argmax over target_logits [T, V] fp32 (~295 MB, memory-bound).
//   One WAVE per 5120-element chunk (V=128000 -> exactly 25 chunks/row, zero
//   tail). Inner loop fully unrolled: 5 groups x 4 independent float4 loads
//   -> 4+ loads in flight per wave (round-3 lesson: un-unrolled loop kept
//   ~1 outstanding load -> latency-bound collapse). No LDS, no syncthreads.
// Phase 2: one 64-thread block per batch row reduces the 25 chunk partials
//   per draft token and runs the accept/reject scan.
// ---------------------------------------------------------------------------

typedef float f32x4 __attribute__((ext_vector_type(4)));

constexpr int U_F4        = 20;            // float4 per thread per chunk
constexpr int CHUNK_ELEMS = 64 * 4 * U_F4; // 5120 elements per wave-chunk

__device__ __forceinline__ void combine(float& bv, int& bi, float v, int i) {
    // prefer larger value; on tie prefer smaller index (jnp.argmax semantics)
    if (v > bv || (v == bv && i < bi)) { bv = v; bi = i; }
}

template <int BLOCK, bool EXACT>
__global__ void __launch_bounds__(BLOCK)
argmax_wave_chunks(const float* __restrict__ logits, int vocab,
                   int chunks_per_row, int nwaves,
                   float* __restrict__ ws_val, int* __restrict__ ws_idx) {
    const int wid = blockIdx.x * (BLOCK / 64) + (threadIdx.x >> 6);
    if (wid >= nwaves) return;
    const int lane = threadIdx.x & 63;
    const int row  = wid / chunks_per_row;
    const int ch   = wid - row * chunks_per_row;
    const int chunk_beg = ch * CHUNK_ELEMS;              // element offset in row
    const float* base = logits + (size_t)row * (size_t)vocab + chunk_beg;
    const f32x4* p4 = (const f32x4*)base;                // 16B-aligned (chunk_beg%5120==0)

    // 4 independent accumulators (one per float4 component). Indices are
    // LOCAL element offsets within the chunk; strictly increasing per accum,
    // so strict '>' gives first-occurrence tie-break for free.
    float bv0 = -INFINITY, bv1 = -INFINITY, bv2 = -INFINITY, bv3 = -INFINITY;
    int   bj0 = 0, bj1 = 1, bj2 = 2, bj3 = 3;

    if (EXACT) {
        #pragma unroll
        for (int g = 0; g < U_F4; g += 4) {
            // 4 independent loads issued back-to-back (addresses don't depend
            // on the accumulators) -> 4 outstanding vmem ops per wave.
            const f32x4 a = __builtin_nontemporal_load(p4 + (g + 0) * 64 + lane);
            const f32x4 b = __builtin_nontemporal_load(p4 + (g + 1) * 64 + lane);
            const f32x4 c = __builtin_nontemporal_load(p4 + (g + 2) * 64 + lane);
            const f32x4 d = __builtin_nontemporal_load(p4 + (g + 3) * 64 + lane);
            const int ea = ((g + 0) * 64 + lane) << 2;
            const int eb = ((g + 1) * 64 + lane) << 2;
            const int ec = ((g + 2) * 64 + lane) << 2;
            const int ed = ((g + 3) * 64 + lane) << 2;
            if (a.x > bv0) { bv0 = a.x; bj0 = ea; }
            if (a.y > bv1) { bv1 = a.y; bj1 = ea + 1; }
            if (a.z > bv2) { bv2 = a.z; bj2 = ea + 2; }
            if (a.w > bv3) { bv3 = a.w; bj3 = ea + 3; }
            if (b.x > bv0) { bv0 = b.x; bj0 = eb; }
            if (b.y > bv1) { bv1 = b.y; bj1 = eb + 1; }
            if (b.z > bv2) { bv2 = b.z; bj2 = eb + 2; }
            if (b.w > bv3) { bv3 = b.w; bj3 = eb + 3; }
            if (c.x > bv0) { bv0 = c.x; bj0 = ec; }
            if (c.y > bv1) { bv1 = c.y; bj1 = ec + 1; }
            if (c.z > bv2) { bv2 = c.z; bj2 = ec + 2; }
            if (c.w > bv3) { bv3 = c.w; bj3 = ec + 3; }
            if (d.x > bv0) { bv0 = d.x; bj0 = ed; }
            if (d.y > bv1) { bv1 = d.y; bj1 = ed + 1; }
            if (d.z > bv2) { bv2 = d.z; bj2 = ed + 2; }
            if (d.w > bv3) { bv3 = d.w; bj3 = ed + 3; }
        }
    } else {
        const int chunk_len = min(CHUNK_ELEMS, vocab - chunk_beg);
        const int n4 = chunk_len >> 2;
        for (int s = lane; s < n4; s += 64) {
            const f32x4 a = __builtin_nontemporal_load(p4 + s);
            const int e = s << 2;
            if (a.x > bv0) { bv0 = a.x; bj0 = e; }
            if (a.y > bv1) { bv1 = a.y; bj1 = e + 1; }
            if (a.z > bv2) { bv2 = a.z; bj2 = e + 2; }
            if (a.w > bv3) { bv3 = a.w; bj3 = e + 3; }
        }
        for (int e = (n4 << 2) + lane; e < chunk_len; e += 64)
            combine(bv0, bj0, base[e], e);
    }

    // merge 4 accumulators (tie -> smaller element index)
    float bv = bv0; int bi = bj0;
    combine(bv, bi, bv1, bj1);
    combine(bv, bi, bv2, bj2);
    combine(bv, bi, bv3, bj3);
    bi += chunk_beg;                                     // within-row index

    // 64-lane wave reduce
    #pragma unroll
    for (int off = 32; off >= 1; off >>= 1) {
        float ov = __shfl_down(bv, off, 64);
        int   oi = __shfl_down(bi, off, 64);
        combine(bv, bi, ov, oi);
    }
    if (lane == 0) { ws_val[wid] = bv; ws_idx[wid] = bi; }
}

__global__ void __launch_bounds__(64)
finalize_kernel(const int* __restrict__ draft,
                const int* __restrict__ cu,
                const float* __restrict__ ws_val,
                const int* __restrict__ ws_idx,
                const int* __restrict__ bonus,
                int* __restrict__ out_tokens,   // [B, S+1]
                int* __restrict__ out_bonus,    // [B]
                int chunks_per_row, int S) {
    const int b = blockIdx.x;
    const int lane = threadIdx.x;
    const int start = (b == 0) ? 0 : cu[b - 1];
    const int n = cu[b] - start;                 // in [1, S]

    __shared__ int tok[32];
    if (lane < n && lane < 32) {
        const int base = (start + lane) * chunks_per_row;
        float bv = -INFINITY;
        int   bi = 0x7fffffff;
        for (int k = 0; k < chunks_per_row; ++k)
            combine(bv, bi, ws_val[base + k], ws_idx[base + k]);
        tok[lane] = bi;
    }
    __syncthreads();
    if (lane == 0) {
        int* rowo = out_tokens + (size_t)b * (S + 1);
        bool rejected  = false;
        int  processed = 0;
        for (int p = 0; p <= S; ++p) {
            int val;
            if (p < n) {
                if (!rejected) {
                    const int t = tok[p];
                    val = t;
                    ++processed;
                    if (draft[start + p] != t) rejected = true;  // argmax AT mismatch pos
                } else {
                    val = -1;                                    // after first mismatch
                }
            } else if (p == n) {
                val = rejected ? -1 : bonus[b];                  // bonus slot
            } else {
                val = -1;                                        // past bonus
            }
            rowo[p] = val;
        }
        out_bonus[b] = processed - 1 + (rejected ? 0 : 1);
    }
}

extern "C" void kernel_launch(void* const* d_in, const int* in_sizes, int n_in,
                              void* d_out, int out_size, void* d_ws, size_t ws_size,
                              hipStream_t stream) {
    // Inputs (setup_inputs order):
    //   0: draft_token_ids     int32 [T]
    //   1: num_spec_steps      int32 [1]   (derived host-side instead)
    //   2: cu_num_draft_tokens int32 [B]
    //   3: target_logits       float32 [T, V]
    //   4: bonus_token_ids     int32 [B]
    const int*   draft  = (const int*)d_in[0];
    const int*   cu     = (const int*)d_in[2];
    const float* logits = (const float*)d_in[3];
    const int*   bonus  = (const int*)d_in[4];

    const int T     = in_sizes[0];
    const int B     = in_sizes[2];
    const int vocab = in_sizes[3] / T;
    const int S     = out_size / B - 2;   // out = B*(S+1) + B

    constexpr int BLOCK = 256;            // 4 independent waves per block
    const bool exact = (vocab % CHUNK_ELEMS) == 0;
    const int cpr    = (vocab + CHUNK_ELEMS - 1) / CHUNK_ELEMS;  // 25 for V=128000
    const int nwaves = T * cpr;                                  // 14400
    const int blocks = (nwaves + (BLOCK / 64) - 1) / (BLOCK / 64);

    float* ws_val = (float*)d_ws;                  // T*cpr floats
    int*   ws_idx = (int*)(ws_val + (size_t)T * cpr);
    int* out_tokens = (int*)d_out;                 // [B, S+1]
    int* out_bonus  = out_tokens + (size_t)B * (S + 1);

    if (exact) {
        argmax_wave_chunks<BLOCK, true><<<blocks, BLOCK, 0, stream>>>(
            logits, vocab, cpr, nwaves, ws_val, ws_idx);
    } else {
        argmax_wave_chunks<BLOCK, false><<<blocks, BLOCK, 0, stream>>>(
            logits, vocab, cpr, nwaves, ws_val, ws_idx);
    }
    finalize_kernel<<<B, 64, 0, stream>>>(
        draft, cu, ws_val, ws_idx, bonus, out_tokens, out_bonus, cpr, S);
}